// Round 5
// baseline (244.473 us; speedup 1.0000x reference)
//
#include <hip/hip_runtime.h>
#include <hip/hip_bf16.h>

typedef __attribute__((ext_vector_type(8))) short short8;
typedef __attribute__((ext_vector_type(4))) float floatx4;

#define MFMA16(a, b, c) __builtin_amdgcn_mfma_f32_16x16x32_bf16((a), (b), (c), 0, 0, 0)

__device__ __forceinline__ short f2bf(float f) {
    union { float f; unsigned u; } x; x.f = f;
    unsigned r = (x.u + 0x7fffu + ((x.u >> 16) & 1u)) >> 16;
    return (short)r;
}
__device__ __forceinline__ float bf2f(short s) {
    union { float f; unsigned u; } x; x.u = ((unsigned)(unsigned short)s) << 16;
    return x.f;
}

// async global->LDS, 16B per lane; LDS dest is wave-uniform base + lane*16
__device__ __forceinline__ void gl2lds16(const short* g, short* l) {
    void* gv = const_cast<short*>(g);
    __builtin_amdgcn_global_load_lds((__attribute__((address_space(1))) void*)gv,
                                     (__attribute__((address_space(3))) void*)l,
                                     16, 0, 0);
}

// ------------- weight prep (one launch): copies, transposes, bias-fold dots -------------
// z=0: Wq->wqb bf16 copy + wu += Wq·bk row-dots + cst; z=1: Wk->wkb + wv2 += Wk·bq
// z=2: transpose Wv -> Wtv rows [512,1024); z=3: transpose Wn -> Wn_t
__global__ void prep_w(const float* __restrict__ Wq, const float* __restrict__ Wk,
                       const float* __restrict__ Wv, const float* __restrict__ Wn,
                       const float* __restrict__ bq, const float* __restrict__ bk,
                       short* __restrict__ wqb, short* __restrict__ wkb,
                       short* __restrict__ Wtv, short* __restrict__ Wn_t,
                       float* __restrict__ wu, float* __restrict__ wv2,
                       float* __restrict__ cstp) {
    __shared__ float t[32][33];
    int z = blockIdx.z;
    int o0 = blockIdx.x * 32, c0 = blockIdx.y * 32;
    int lx = threadIdx.x, ly = threadIdx.y;   // (32,8)
    if (z < 2) {
        const float* src  = z ? Wk : Wq;
        const float* bvec = z ? bq : bk;
        short* dst  = z ? wkb : wqb;
        float* ddst = z ? wv2 : wu;
        float bvl = bvec[o0 + lx];
        for (int i = ly; i < 32; i += 8) {
            float v = src[(size_t)(c0 + i) * 512 + o0 + lx];
            dst[(size_t)(c0 + i) * 512 + o0 + lx] = f2bf(v);
            float d = v * bvl;
#pragma unroll
            for (int off = 16; off > 0; off >>= 1) d += __shfl_down(d, off, 32);
            if (lx == 0) atomicAdd(&ddst[c0 + i], d);
        }
        if (z == 0 && blockIdx.x == 0 && blockIdx.y == 0) {
            int t0 = ly * 32 + lx;
            atomicAdd(cstp, bq[t0] * bk[t0] + bq[t0 + 256] * bk[t0 + 256]);
        }
    } else {
        const float* src = (z == 2) ? Wv : Wn;
        short* dst = (z == 2) ? (Wtv + (size_t)512 * 512) : Wn_t;
        for (int i = ly; i < 32; i += 8) t[i][lx] = src[(size_t)(c0 + i) * 512 + o0 + lx];
        __syncthreads();
        for (int i = ly; i < 32; i += 8) dst[(size_t)(o0 + i) * 512 + c0 + lx] = f2bf(t[lx][i]);
    }
}

// ------------- G = Wk·Wq^T (bf16), into Wtv rows [0,512) -------------
__global__ __launch_bounds__(256) void g_gemm(const short* __restrict__ A,
                                              const short* __restrict__ B,
                                              short* __restrict__ Out) {
    const int tid = threadIdx.x;
    const int wv = tid >> 6, ln = tid & 63;
    const int m0 = blockIdx.x * 128, n0 = blockIdx.y * 128;
    __shared__ __attribute__((aligned(16))) short As[128 * 32];
    __shared__ __attribute__((aligned(16))) short Bs[128 * 32];
    floatx4 acc[4][4] = {};
    const int wm = (wv >> 1) * 64, wn = (wv & 1) * 64;
    const int fr = ln & 15, fq = ln >> 4;
    for (int kk = 0; kk < 512; kk += 32) {
        __syncthreads();
#pragma unroll
        for (int j = 0; j < 2; ++j) {
            int s = (wv * 2 + j) * 64 + ln;
            int r = s >> 2;
            int q = (s & 3) ^ ((r >> 1) & 3);
            gl2lds16(A + (size_t)(m0 + r) * 512 + kk + q * 8, As + (size_t)(wv * 2 + j) * 512);
            gl2lds16(B + (size_t)(n0 + r) * 512 + kk + q * 8, Bs + (size_t)(wv * 2 + j) * 512);
        }
        __syncthreads();
        short8 af[4], bfr[4];
#pragma unroll
        for (int t = 0; t < 4; ++t) {
            int ra = wm + t * 16 + fr;
            af[t]  = *(const short8*)(As + ra * 32 + ((fq ^ ((ra >> 1) & 3)) * 8));
            int rb = wn + t * 16 + fr;
            bfr[t] = *(const short8*)(Bs + rb * 32 + ((fq ^ ((rb >> 1) & 3)) * 8));
        }
#pragma unroll
        for (int mt = 0; mt < 4; ++mt)
#pragma unroll
            for (int nt = 0; nt < 4; ++nt)
                acc[mt][nt] = MFMA16(af[mt], bfr[nt], acc[mt][nt]);
    }
#pragma unroll
    for (int mt = 0; mt < 4; ++mt)
#pragma unroll
        for (int nt = 0; nt < 4; ++nt) {
            int n = n0 + wn + nt * 16 + fr;
#pragma unroll
            for (int r = 0; r < 4; ++r) {
                int m = m0 + wm + mt * 16 + fq * 4 + r;
                Out[(size_t)m * 512 + n] = f2bf(acc[mt][nt][r]);
            }
        }
}

// ---- groupnorm: x[b][c][p] -> hnt[b][p][c] (natural) + Hp[b][perm(p)][c], + u1p/v2p dots ----
__global__ __launch_bounds__(256) void groupnorm_k(const float* __restrict__ x,
                                                   const float* __restrict__ wu,
                                                   const float* __restrict__ wv2,
                                                   short* __restrict__ hnt,
                                                   short* __restrict__ Hp,
                                                   float* __restrict__ u1p,
                                                   float* __restrict__ v2p) {
    int b = blockIdx.x >> 5, g = blockIdx.x & 31;
    const float* xg = x + ((size_t)b * 512 + g * 16) * 1024;   // 16 rows x 1024
    const float4* xg4 = (const float4*)xg;
    float s = 0.f, ss = 0.f;
    for (int i = threadIdx.x; i < 4096; i += 256) {
        float4 v = xg4[i];
        s  += v.x + v.y + v.z + v.w;
        ss += v.x * v.x + v.y * v.y + v.z * v.z + v.w * v.w;
    }
#pragma unroll
    for (int off = 32; off > 0; off >>= 1) {
        s  += __shfl_down(s,  off, 64);
        ss += __shfl_down(ss, off, 64);
    }
    __shared__ float red[8];
    __shared__ float wus[16], wvs[16];
    int w = threadIdx.x >> 6;
    if ((threadIdx.x & 63) == 0) { red[w] = s; red[4 + w] = ss; }
    if (threadIdx.x < 16) wus[threadIdx.x] = wu[g * 16 + threadIdx.x];
    else if (threadIdx.x < 32) wvs[threadIdx.x - 16] = wv2[g * 16 + threadIdx.x - 16];
    __syncthreads();
    float S  = red[0] + red[1] + red[2] + red[3];
    float SS = red[4] + red[5] + red[6] + red[7];
    float mean = S * (1.f / 16384.f);
    float var  = SS * (1.f / 16384.f) - mean * mean;
    float rstd = rsqrtf(var + 1e-5f);
    __shared__ __attribute__((aligned(16))) short tile[16 * 1026];
    for (int i = threadIdx.x; i < 4096; i += 256) {
        float4 v = xg4[i];
        int c = i >> 8, p = (i & 255) * 4;
        short* tp = tile + c * 1026 + p;
        tp[0] = f2bf((v.x - mean) * rstd);
        tp[1] = f2bf((v.y - mean) * rstd);
        tp[2] = f2bf((v.z - mean) * rstd);
        tp[3] = f2bf((v.w - mean) * rstd);
    }
    __syncthreads();
    for (int i = threadIdx.x; i < 2048; i += 256) {
        int p = i >> 1, half = i & 1;
        int pp = ((p & 31) << 5) | (p >> 5);
        short8 v;
#pragma unroll
        for (int j = 0; j < 8; ++j) v[j] = tile[(half * 8 + j) * 1026 + p];
        *(short8*)(hnt + ((size_t)b * 1024 + p)  * 512 + g * 16 + half * 8) = v;
        *(short8*)(Hp  + ((size_t)b * 1024 + pp) * 512 + g * 16 + half * 8) = v;
    }
    // per-position partial dots for bias folding (this group's 16 channels)
    for (int p = threadIdx.x; p < 1024; p += 256) {
        float su = 0.f, sv = 0.f;
#pragma unroll
        for (int c = 0; c < 16; ++c) {
            float hv = bf2f(tile[c * 1026 + p]);
            su += hv * wus[c];
            sv += hv * wvs[c];
        }
        int pp = ((p & 31) << 5) | (p >> 5);
        atomicAdd(&u1p[b * 1024 + pp], su);
        atomicAdd(&v2p[b * 1024 + pp], sv);
    }
}

// ------------- fused T/V GEMM: 128x128, N=1024 over [G ; Wv_t] -------------
// n<512 -> T = hn·G^T rows written PERMUTED; n>=512 -> Vb = hn·Wv + bv natural.
__global__ __launch_bounds__(256) void tv_gemm(const short* __restrict__ A,
                                               const short* __restrict__ Wt,
                                               const float* __restrict__ bv,
                                               short* __restrict__ T,
                                               short* __restrict__ Vb) {
    const int tid = threadIdx.x;
    const int wv = tid >> 6, ln = tid & 63;
    int sid = blockIdx.x + 8 * (blockIdx.y + 8 * blockIdx.z);
    int xcd = sid & 7, chunk = sid >> 3;           // XCD batch-affinity swizzle
    int bz = xcd * 2 + (chunk >> 6);
    int inner = chunk & 63;
    const int m0 = (inner & 7) * 128, n0 = (inner >> 3) * 128;
    const size_t BS = 1024 * 512;
    const short* Ab = A + (size_t)bz * BS;
    const int tsel = n0 >> 9;
    short* Ob = (tsel ? Vb : T) + (size_t)bz * BS;

    __shared__ __attribute__((aligned(16))) short As[128 * 32];
    __shared__ __attribute__((aligned(16))) short Bs[128 * 32];

    floatx4 acc[4][4] = {};
    const int wm = (wv >> 1) * 64, wn = (wv & 1) * 64;
    const int fr = ln & 15, fq = ln >> 4;

    for (int kk = 0; kk < 512; kk += 32) {
        __syncthreads();
#pragma unroll
        for (int j = 0; j < 2; ++j) {
            int s = (wv * 2 + j) * 64 + ln;
            int r = s >> 2;
            int q = (s & 3) ^ ((r >> 1) & 3);
            gl2lds16(Ab + (size_t)(m0 + r) * 512 + kk + q * 8, As + (size_t)(wv * 2 + j) * 512);
            gl2lds16(Wt + (size_t)(n0 + r) * 512 + kk + q * 8, Bs + (size_t)(wv * 2 + j) * 512);
        }
        __syncthreads();
        short8 af[4], bfr[4];
#pragma unroll
        for (int t = 0; t < 4; ++t) {
            int ra = wm + t * 16 + fr;
            af[t]  = *(const short8*)(As + ra * 32 + ((fq ^ ((ra >> 1) & 3)) * 8));
            int rb = wn + t * 16 + fr;
            bfr[t] = *(const short8*)(Bs + rb * 32 + ((fq ^ ((rb >> 1) & 3)) * 8));
        }
#pragma unroll
        for (int mt = 0; mt < 4; ++mt)
#pragma unroll
            for (int nt = 0; nt < 4; ++nt)
                acc[mt][nt] = MFMA16(af[mt], bfr[nt], acc[mt][nt]);
    }
#pragma unroll
    for (int mt = 0; mt < 4; ++mt)
#pragma unroll
        for (int nt = 0; nt < 4; ++nt) {
            int n = n0 + wn + nt * 16 + fr;
            float bvv = tsel ? bv[n - 512] : 0.0f;
            int nn = n & 511;
#pragma unroll
            for (int r = 0; r < 4; ++r) {
                int m = m0 + wm + mt * 16 + fq * 4 + r;
                int mrow = tsel ? m : (((m & 31) << 5) | (m >> 5));
                Ob[(size_t)mrow * 512 + nn] = f2bf(acc[mt][nt][r] + bvv);
            }
        }
}

// ------- fused S-GEMM + softmax diagonal; contiguous reads of T (permuted) & Hp -------
__global__ __launch_bounds__(256, 2) void attn_sm(const short* __restrict__ Tt,
                                                  const short* __restrict__ Hp,
                                                  const float* __restrict__ u1p,
                                                  const float* __restrict__ v2p,
                                                  const float* __restrict__ cstp,
                                                  float* __restrict__ Dm) {
    const int tid = threadIdx.x;
    const int wv = tid >> 6, ln = tid & 63;
    int sid = blockIdx.x + 8 * (blockIdx.y + 4 * blockIdx.z);
    int xcd = sid & 7, chunk = sid >> 3;           // XCD batch-affinity swizzle
    int b = xcd * 2 + (chunk >> 5);
    int inner = chunk & 31;
    const int m0 = (inner & 7) * 128, n0 = (inner >> 3) * 256;
    const short* Tb = Tt + (size_t)b * (1024 * 512);
    const short* Hb = Hp + (size_t)b * (1024 * 512);

    __shared__ __attribute__((aligned(16))) short As[128 * 32];
    __shared__ __attribute__((aligned(16))) short Bs[256 * 32];

    floatx4 acc[4][8] = {};
    const int wm = (wv >> 1) * 64, wn = (wv & 1) * 128;
    const int fr = ln & 15, fq = ln >> 4;

    for (int kk = 0; kk < 512; kk += 32) {
        __syncthreads();
#pragma unroll
        for (int j = 0; j < 2; ++j) {
            int s = (wv * 2 + j) * 64 + ln;
            int r = s >> 2;
            int q = (s & 3) ^ ((r >> 1) & 3);
            gl2lds16(Tb + (size_t)(m0 + r) * 512 + kk + q * 8, As + (size_t)(wv * 2 + j) * 512);
        }
#pragma unroll
        for (int j = 0; j < 4; ++j) {
            int s = (wv * 4 + j) * 64 + ln;
            int r = s >> 2;
            int q = (s & 3) ^ ((r >> 1) & 3);
            gl2lds16(Hb + (size_t)(n0 + r) * 512 + kk + q * 8, Bs + (size_t)(wv * 4 + j) * 512);
        }
        __syncthreads();
        short8 af[4], bfr[8];
#pragma unroll
        for (int t = 0; t < 4; ++t) {
            int ra = wm + t * 16 + fr;
            af[t] = *(const short8*)(As + ra * 32 + ((fq ^ ((ra >> 1) & 3)) * 8));
        }
#pragma unroll
        for (int u = 0; u < 8; ++u) {
            int rb = wn + u * 16 + fr;
            bfr[u] = *(const short8*)(Bs + rb * 32 + ((fq ^ ((rb >> 1) & 3)) * 8));
        }
#pragma unroll
        for (int mt = 0; mt < 4; ++mt)
#pragma unroll
            for (int nt = 0; nt < 8; ++nt)
                acc[mt][nt] = MFMA16(af[mt], bfr[nt], acc[mt][nt]);
    }

    // ---- per-slice softmax-diagonal (2x4 = 8 slices per wave) ----
    const float scale = 0.04419417382415922f;  // 512^-0.5
    const float cst = cstp[0];
    const int wbase = (m0 + wm) >> 5;
    const int Wbase = (n0 + wn) >> 5;
#pragma unroll
    for (int si = 0; si < 2; ++si) {
#pragma unroll
        for (int sj = 0; sj < 4; ++sj) {
            int wg = wbase + si, Wg = Wbase + sj;
            float tv[16];
            float mx = -3.0e38f;
#pragma unroll
            for (int mi = 0; mi < 2; ++mi)
#pragma unroll
                for (int ni = 0; ni < 2; ++ni) {
                    float vc = v2p[b * 1024 + Wg * 32 + ni * 16 + fr];
#pragma unroll
                    for (int r = 0; r < 4; ++r) {
                        float uc = u1p[b * 1024 + wg * 32 + mi * 16 + fq * 4 + r];
                        float u = (acc[2 * si + mi][2 * sj + ni][r] + uc + vc + cst) * scale;
                        tv[(mi * 2 + ni) * 4 + r] = u;
                        mx = fmaxf(mx, u);
                    }
                }
#pragma unroll
            for (int off = 32; off > 0; off >>= 1) mx = fmaxf(mx, __shfl_xor(mx, off, 64));
            float se = 0.f;
#pragma unroll
            for (int i = 0; i < 16; ++i) se += __expf(tv[i] - mx);
#pragma unroll
            for (int off = 32; off > 0; off >>= 1) se += __shfl_xor(se, off, 64);
            if (fq == ((wg >> 2) & 3) && fr == (Wg & 15)) {
                int mi = wg >> 4, ni = Wg >> 4;
                float numer = tv[(mi * 2 + ni) * 4 + (wg & 3)];
                Dm[((size_t)b * 32 + wg) * 32 + Wg] = __expf(numer - mx) / se;
            }
        }
    }
}

// ---------------- fused out-GEMM: out[b][n][m] = x + D[b][m]*(V·Wn)[m][n] + bn[n] ----------------
__global__ __launch_bounds__(256) void out_gemm(const short* __restrict__ A,
                                                const short* __restrict__ Wt,
                                                const float* __restrict__ Dm,
                                                const float* __restrict__ bnb,
                                                const float* __restrict__ x,
                                                float* __restrict__ out) {
    const int tid = threadIdx.x;
    const int wv = tid >> 6, ln = tid & 63;
    int sid = blockIdx.x + 8 * (blockIdx.y + 4 * blockIdx.z);
    int xcd = sid & 7, chunk = sid >> 3;           // XCD batch-affinity swizzle
    int b = xcd * 2 + (chunk >> 5);
    int inner = chunk & 31;
    const int m0 = (inner & 7) * 128, n0 = (inner >> 3) * 128;
    const size_t BS = 1024 * 512;
    const short* Ab = A + (size_t)b * BS;

    __shared__ __attribute__((aligned(16))) short As[128 * 32];
    __shared__ __attribute__((aligned(16))) short Bs[128 * 32];

    floatx4 acc[4][4] = {};
    const int wm = (wv >> 1) * 64, wn = (wv & 1) * 64;
    const int fr = ln & 15, fq = ln >> 4;

    for (int kk = 0; kk < 512; kk += 32) {
        __syncthreads();
#pragma unroll
        for (int j = 0; j < 2; ++j) {
            int s = (wv * 2 + j) * 64 + ln;
            int r = s >> 2;
            int q = (s & 3) ^ ((r >> 1) & 3);
            gl2lds16(Ab + (size_t)(m0 + r) * 512 + kk + q * 8, As + (size_t)(wv * 2 + j) * 512);
            gl2lds16(Wt + (size_t)(n0 + r) * 512 + kk + q * 8, Bs + (size_t)(wv * 2 + j) * 512);
        }
        __syncthreads();
        short8 af[4], bfr[4];
#pragma unroll
        for (int t = 0; t < 4; ++t) {
            int ra = wm + t * 16 + fr;
            af[t]  = *(const short8*)(As + ra * 32 + ((fq ^ ((ra >> 1) & 3)) * 8));
            int rb = wn + t * 16 + fr;
            bfr[t] = *(const short8*)(Bs + rb * 32 + ((fq ^ ((rb >> 1) & 3)) * 8));
        }
#pragma unroll
        for (int mt = 0; mt < 4; ++mt)
#pragma unroll
            for (int nt = 0; nt < 4; ++nt)
                acc[mt][nt] = MFMA16(af[mt], bfr[nt], acc[mt][nt]);
    }
#pragma unroll
    for (int mt = 0; mt < 4; ++mt) {
        int mbase = m0 + wm + mt * 16 + fq * 4;
        float4 d4 = *(const float4*)(Dm + (size_t)b * 1024 + mbase);
#pragma unroll
        for (int nt = 0; nt < 4; ++nt) {
            int n = n0 + wn + nt * 16 + fr;
            float bvv = bnb[n];
            size_t base = ((size_t)b * 512 + n) * 1024 + mbase;
            float4 x4 = *(const float4*)(x + base);
            float4 o;
            o.x = x4.x + d4.x * acc[mt][nt][0] + bvv;
            o.y = x4.y + d4.y * acc[mt][nt][1] + bvv;
            o.z = x4.z + d4.z * acc[mt][nt][2] + bvv;
            o.w = x4.w + d4.w * acc[mt][nt][3] + bvv;
            *(float4*)(out + base) = o;
        }
    }
}

extern "C" void kernel_launch(void* const* d_in, const int* in_sizes, int n_in,
                              void* d_out, int out_size, void* d_ws, size_t ws_size,
                              hipStream_t stream) {
    const float* x  = (const float*)d_in[0];
    const float* Wq = (const float*)d_in[1];
    const float* bq = (const float*)d_in[2];
    const float* Wk = (const float*)d_in[3];
    const float* bk = (const float*)d_in[4];
    const float* Wv = (const float*)d_in[5];
    const float* bv = (const float*)d_in[6];
    const float* Wn = (const float*)d_in[7];
    const float* bn = (const float*)d_in[8];
    float* out = (float*)d_out;
    char* ws = (char*)d_ws;

    const size_t WSZ = (size_t)512 * 512 * 2;        // bf16 512x512
    const size_t TSZ = (size_t)16 * 1024 * 512 * 2;  // bf16 activation tensor
    short* Wtv  = (short*)(ws);                      // [1024][512]: G rows 0-511, Wv_t rows 512-1023
    short* Wn_t = (short*)(ws + 2 * WSZ);
    // zero-init accumulator region (one memset): wu, wv2, cst, u1p, v2p
    float* wu   = (float*)(ws + 3 * WSZ);            // 512
    float* wv2  = wu + 512;                          // 512
    float* cstp = wv2 + 512;                         // 16 (pad)
    float* u1p  = cstp + 16;                         // 16384
    float* v2p  = u1p + 16384;                       // 16384
    const size_t ZB = (512 + 512 + 16 + 16384 + 16384) * sizeof(float);
    char* base = ws + 3 * WSZ + 139264;              // 136 KB zeros, padded
    short* hnt = (short*)(base);
    short* Hp  = (short*)(base + TSZ);
    short* T   = (short*)(base + 2 * TSZ);
    short* Vb  = (short*)(base + 3 * TSZ);
    float* Dm  = (float*)(base + 4 * TSZ);           // 64 KB
    // wqb/wkb alias the head of Hp (dead before groupnorm writes Hp)
    short* wqb = Hp;
    short* wkb = Hp + 512 * 512;

    hipMemsetAsync(wu, 0, ZB, stream);
    prep_w<<<dim3(16, 16, 4), dim3(32, 8), 0, stream>>>(
        Wq, Wk, Wv, Wn, bq, bk, wqb, wkb, Wtv, Wn_t, wu, wv2, cstp);
    g_gemm<<<dim3(4, 4, 1), 256, 0, stream>>>(wkb, wqb, Wtv);
    groupnorm_k<<<512, 256, 0, stream>>>(x, wu, wv2, hnt, Hp, u1p, v2p);
    tv_gemm<<<dim3(8, 8, 16), 256, 0, stream>>>(hnt, Wtv, bv, T, Vb);
    attn_sm<<<dim3(8, 4, 16), 256, 0, stream>>>(T, Hp, u1p, v2p, cstp, Dm);
    out_gemm<<<dim3(8, 4, 16), 256, 0, stream>>>(Vb, Wn_t, Dm, bn, x, out);
}

// Round 6
// 219.513 us; speedup vs baseline: 1.1137x; 1.1137x over previous
//
#include <hip/hip_runtime.h>
#include <hip/hip_bf16.h>

typedef __attribute__((ext_vector_type(8))) short short8;
typedef __attribute__((ext_vector_type(4))) float floatx4;

#define MFMA16(a, b, c) __builtin_amdgcn_mfma_f32_16x16x32_bf16((a), (b), (c), 0, 0, 0)

__device__ __forceinline__ short f2bf(float f) {
    union { float f; unsigned u; } x; x.f = f;
    unsigned r = (x.u + 0x7fffu + ((x.u >> 16) & 1u)) >> 16;
    return (short)r;
}
__device__ __forceinline__ float bf2f(short s) {
    union { float f; unsigned u; } x; x.u = ((unsigned)(unsigned short)s) << 16;
    return x.f;
}

// async global->LDS, 16B per lane; LDS dest is wave-uniform base + lane*16
__device__ __forceinline__ void gl2lds16(const short* g, short* l) {
    void* gv = const_cast<short*>(g);
    __builtin_amdgcn_global_load_lds((__attribute__((address_space(1))) void*)gv,
                                     (__attribute__((address_space(3))) void*)l,
                                     16, 0, 0);
}

// ------------- weight prep (one launch, grid z=0..4) -------------
// z=0: Wq->wqb bf16 copy; z=1: Wk->wkb; z=2: transpose Wv -> Wtv rows [512,1024);
// z=3: transpose Wn -> Wn_t; z=4 (y==0 only): wu=Wq·bk, wv2=Wk·bq row-dots + cst=bq·bk.
__global__ void prep_w(const float* __restrict__ Wq, const float* __restrict__ Wk,
                       const float* __restrict__ Wv, const float* __restrict__ Wn,
                       const float* __restrict__ bq, const float* __restrict__ bk,
                       short* __restrict__ wqb, short* __restrict__ wkb,
                       short* __restrict__ Wtv, short* __restrict__ Wn_t,
                       float* __restrict__ wu, float* __restrict__ wv2,
                       float* __restrict__ cstp) {
    __shared__ float t[32][33];
    __shared__ float cred[4];
    int z = blockIdx.z;
    int o0 = blockIdx.x * 32, c0 = blockIdx.y * 32;
    int lx = threadIdx.x, ly = threadIdx.y;   // (32,8)
    int tid = ly * 32 + lx;
    if (z < 2) {
        const float* src = z ? Wk : Wq;
        short* dst = z ? wkb : wqb;
        for (int i = ly; i < 32; i += 8)
            dst[(size_t)(c0 + i) * 512 + o0 + lx] = f2bf(src[(size_t)(c0 + i) * 512 + o0 + lx]);
    } else if (z < 4) {
        const float* src = (z == 2) ? Wv : Wn;
        short* dst = (z == 2) ? (Wtv + (size_t)512 * 512) : Wn_t;
        for (int i = ly; i < 32; i += 8) t[i][lx] = src[(size_t)(c0 + i) * 512 + o0 + lx];
        __syncthreads();
        for (int i = ly; i < 32; i += 8) dst[(size_t)(o0 + i) * 512 + c0 + lx] = f2bf(t[lx][i]);
    } else {
        if (blockIdx.y != 0) return;
        int cb = blockIdx.x * 32;             // 32 channels per block
        int cl = tid >> 3, part = tid & 7;    // 8 partial sums per channel
        float su = 0.f, sv = 0.f;
        const float* wqr = Wq + (size_t)(cb + cl) * 512;
        const float* wkr = Wk + (size_t)(cb + cl) * 512;
        for (int o = part * 64; o < part * 64 + 64; ++o) {
            su += wqr[o] * bk[o];
            sv += wkr[o] * bq[o];
        }
        t[cl][part] = su;
        t[cl][part + 8] = sv;
        // cst (only block x==0)
        float sc = 0.f;
        if (blockIdx.x == 0) sc = bq[tid] * bk[tid] + bq[tid + 256] * bk[tid + 256];
#pragma unroll
        for (int off = 32; off > 0; off >>= 1) sc += __shfl_down(sc, off, 64);
        if ((tid & 63) == 0) cred[tid >> 6] = sc;
        __syncthreads();
        if (part == 0) {
            float a = 0.f, b2 = 0.f;
#pragma unroll
            for (int j = 0; j < 8; ++j) { a += t[cl][j]; b2 += t[cl][j + 8]; }
            wu[cb + cl] = a;
            wv2[cb + cl] = b2;
        }
        if (blockIdx.x == 0 && tid == 0) cstp[0] = cred[0] + cred[1] + cred[2] + cred[3];
    }
}

// ------------- G = Wk·Wq^T (bf16), into Wtv rows [0,512) -------------
__global__ __launch_bounds__(256) void g_gemm(const short* __restrict__ A,
                                              const short* __restrict__ B,
                                              short* __restrict__ Out) {
    const int tid = threadIdx.x;
    const int wv = tid >> 6, ln = tid & 63;
    const int m0 = blockIdx.x * 128, n0 = blockIdx.y * 128;
    __shared__ __attribute__((aligned(16))) short As[128 * 32];
    __shared__ __attribute__((aligned(16))) short Bs[128 * 32];
    floatx4 acc[4][4] = {};
    const int wm = (wv >> 1) * 64, wn = (wv & 1) * 64;
    const int fr = ln & 15, fq = ln >> 4;
    for (int kk = 0; kk < 512; kk += 32) {
        __syncthreads();
#pragma unroll
        for (int j = 0; j < 2; ++j) {
            int s = (wv * 2 + j) * 64 + ln;
            int r = s >> 2;
            int q = (s & 3) ^ ((r >> 1) & 3);
            gl2lds16(A + (size_t)(m0 + r) * 512 + kk + q * 8, As + (size_t)(wv * 2 + j) * 512);
            gl2lds16(B + (size_t)(n0 + r) * 512 + kk + q * 8, Bs + (size_t)(wv * 2 + j) * 512);
        }
        __syncthreads();
        short8 af[4], bfr[4];
#pragma unroll
        for (int t = 0; t < 4; ++t) {
            int ra = wm + t * 16 + fr;
            af[t]  = *(const short8*)(As + ra * 32 + ((fq ^ ((ra >> 1) & 3)) * 8));
            int rb = wn + t * 16 + fr;
            bfr[t] = *(const short8*)(Bs + rb * 32 + ((fq ^ ((rb >> 1) & 3)) * 8));
        }
#pragma unroll
        for (int mt = 0; mt < 4; ++mt)
#pragma unroll
            for (int nt = 0; nt < 4; ++nt)
                acc[mt][nt] = MFMA16(af[mt], bfr[nt], acc[mt][nt]);
    }
#pragma unroll
    for (int mt = 0; mt < 4; ++mt)
#pragma unroll
        for (int nt = 0; nt < 4; ++nt) {
            int n = n0 + wn + nt * 16 + fr;
#pragma unroll
            for (int r = 0; r < 4; ++r) {
                int m = m0 + wm + mt * 16 + fq * 4 + r;
                Out[(size_t)m * 512 + n] = f2bf(acc[mt][nt][r]);
            }
        }
}

// ---------------- groupnorm: x[b][c][p] -> hnt[b][p][c] bf16 (R2-proven) ----------------
__global__ __launch_bounds__(256) void groupnorm_k(const float* __restrict__ x,
                                                   short* __restrict__ hnt) {
    int b = blockIdx.x >> 5, g = blockIdx.x & 31;
    const float* xg = x + ((size_t)b * 512 + g * 16) * 1024;   // 16 rows x 1024
    const float4* xg4 = (const float4*)xg;
    float s = 0.f, ss = 0.f;
    for (int i = threadIdx.x; i < 4096; i += 256) {
        float4 v = xg4[i];
        s  += v.x + v.y + v.z + v.w;
        ss += v.x * v.x + v.y * v.y + v.z * v.z + v.w * v.w;
    }
#pragma unroll
    for (int off = 32; off > 0; off >>= 1) {
        s  += __shfl_down(s,  off, 64);
        ss += __shfl_down(ss, off, 64);
    }
    __shared__ float red[8];
    int w = threadIdx.x >> 6;
    if ((threadIdx.x & 63) == 0) { red[w] = s; red[4 + w] = ss; }
    __syncthreads();
    float S  = red[0] + red[1] + red[2] + red[3];
    float SS = red[4] + red[5] + red[6] + red[7];
    float mean = S * (1.f / 16384.f);
    float var  = SS * (1.f / 16384.f) - mean * mean;
    float rstd = rsqrtf(var + 1e-5f);
    __shared__ __attribute__((aligned(16))) short tile[16 * 1026];
    for (int i = threadIdx.x; i < 4096; i += 256) {
        float4 v = xg4[i];
        int c = i >> 8, p = (i & 255) * 4;
        short* tp = tile + c * 1026 + p;
        tp[0] = f2bf((v.x - mean) * rstd);
        tp[1] = f2bf((v.y - mean) * rstd);
        tp[2] = f2bf((v.z - mean) * rstd);
        tp[3] = f2bf((v.w - mean) * rstd);
    }
    __syncthreads();
    for (int i = threadIdx.x; i < 2048; i += 256) {
        int p = i >> 1, half = i & 1;
        short8 v;
#pragma unroll
        for (int j = 0; j < 8; ++j) v[j] = tile[(half * 8 + j) * 1026 + p];
        *(short8*)(hnt + ((size_t)b * 1024 + p) * 512 + g * 16 + half * 8) = v;
    }
}

// ------------- u1p/v2p: per-row dots of hnt with wu/wv2, stored at permuted index -------------
__global__ __launch_bounds__(256) void uv_gemv(const short* __restrict__ hnt,
                                               const float* __restrict__ wu,
                                               const float* __restrict__ wv2,
                                               float* __restrict__ u1p,
                                               float* __restrict__ v2p) {
    __shared__ float wus[512], wvs[512];
    for (int i = threadIdx.x; i < 512; i += 256) { wus[i] = wu[i]; wvs[i] = wv2[i]; }
    __syncthreads();
    int wv_ = threadIdx.x >> 6, ln = threadIdx.x & 63;
    int row = blockIdx.x * 4 + wv_;
    int b = row >> 10, p = row & 1023;
    short8 h = *(const short8*)(hnt + (size_t)row * 512 + ln * 8);
    float su = 0.f, sv = 0.f;
#pragma unroll
    for (int j = 0; j < 8; ++j) {
        float hv = bf2f(h[j]);
        su += hv * wus[ln * 8 + j];
        sv += hv * wvs[ln * 8 + j];
    }
#pragma unroll
    for (int off = 32; off > 0; off >>= 1) {
        su += __shfl_down(su, off, 64);
        sv += __shfl_down(sv, off, 64);
    }
    if (ln == 0) {
        int pp = ((p & 31) << 5) | (p >> 5);
        u1p[b * 1024 + pp] = su;
        v2p[b * 1024 + pp] = sv;
    }
}

// ------------- fused T/V GEMM: 128x128, N=1024 over [G ; Wv_t], natural writes -------------
__global__ __launch_bounds__(256) void tv_gemm(const short* __restrict__ A,
                                               const short* __restrict__ Wt,
                                               const float* __restrict__ bv,
                                               short* __restrict__ T,
                                               short* __restrict__ Vb) {
    const int tid = threadIdx.x;
    const int wv = tid >> 6, ln = tid & 63;
    int sid = blockIdx.x + 8 * (blockIdx.y + 8 * blockIdx.z);
    int xcd = sid & 7, chunk = sid >> 3;           // XCD batch-affinity swizzle
    int bz = xcd * 2 + (chunk >> 6);
    int inner = chunk & 63;
    const int m0 = (inner & 7) * 128, n0 = (inner >> 3) * 128;
    const size_t BS = 1024 * 512;
    const short* Ab = A + (size_t)bz * BS;
    const int tsel = n0 >> 9;
    short* Ob = (tsel ? Vb : T) + (size_t)bz * BS;

    __shared__ __attribute__((aligned(16))) short As[128 * 32];
    __shared__ __attribute__((aligned(16))) short Bs[128 * 32];

    floatx4 acc[4][4] = {};
    const int wm = (wv >> 1) * 64, wn = (wv & 1) * 64;
    const int fr = ln & 15, fq = ln >> 4;

    for (int kk = 0; kk < 512; kk += 32) {
        __syncthreads();
#pragma unroll
        for (int j = 0; j < 2; ++j) {
            int s = (wv * 2 + j) * 64 + ln;
            int r = s >> 2;
            int q = (s & 3) ^ ((r >> 1) & 3);
            gl2lds16(Ab + (size_t)(m0 + r) * 512 + kk + q * 8, As + (size_t)(wv * 2 + j) * 512);
            gl2lds16(Wt + (size_t)(n0 + r) * 512 + kk + q * 8, Bs + (size_t)(wv * 2 + j) * 512);
        }
        __syncthreads();
        short8 af[4], bfr[4];
#pragma unroll
        for (int t = 0; t < 4; ++t) {
            int ra = wm + t * 16 + fr;
            af[t]  = *(const short8*)(As + ra * 32 + ((fq ^ ((ra >> 1) & 3)) * 8));
            int rb = wn + t * 16 + fr;
            bfr[t] = *(const short8*)(Bs + rb * 32 + ((fq ^ ((rb >> 1) & 3)) * 8));
        }
#pragma unroll
        for (int mt = 0; mt < 4; ++mt)
#pragma unroll
            for (int nt = 0; nt < 4; ++nt)
                acc[mt][nt] = MFMA16(af[mt], bfr[nt], acc[mt][nt]);
    }
#pragma unroll
    for (int mt = 0; mt < 4; ++mt)
#pragma unroll
        for (int nt = 0; nt < 4; ++nt) {
            int n = n0 + wn + nt * 16 + fr;
            float bvv = tsel ? bv[n - 512] : 0.0f;
            int nn = n & 511;
#pragma unroll
            for (int r = 0; r < 4; ++r) {
                int m = m0 + wm + mt * 16 + fq * 4 + r;
                Ob[(size_t)m * 512 + nn] = f2bf(acc[mt][nt][r] + bvv);
            }
        }
}

// ------- fused S-GEMM + softmax diagonal; permuted staging addresses for T and hnt -------
__global__ __launch_bounds__(256, 2) void attn_sm(const short* __restrict__ Tt,
                                                  const short* __restrict__ Hn,
                                                  const float* __restrict__ u1p,
                                                  const float* __restrict__ v2p,
                                                  const float* __restrict__ cstp,
                                                  float* __restrict__ Dm) {
    const int tid = threadIdx.x;
    const int wv = tid >> 6, ln = tid & 63;
    int sid = blockIdx.x + 8 * (blockIdx.y + 4 * blockIdx.z);
    int xcd = sid & 7, chunk = sid >> 3;           // XCD batch-affinity swizzle
    int b = xcd * 2 + (chunk >> 5);
    int inner = chunk & 31;
    const int m0 = (inner & 7) * 128, n0 = (inner >> 3) * 256;
    const short* Tb = Tt + (size_t)b * (1024 * 512);
    const short* Hb = Hn + (size_t)b * (1024 * 512);

    __shared__ __attribute__((aligned(16))) short As[128 * 32];
    __shared__ __attribute__((aligned(16))) short Bs[256 * 32];

    floatx4 acc[4][8] = {};
    const int wm = (wv >> 1) * 64, wn = (wv & 1) * 128;
    const int fr = ln & 15, fq = ln >> 4;

    // loop-invariant staging offsets (permuted source rows)
    size_t offA[2], offB[4];
#pragma unroll
    for (int j = 0; j < 2; ++j) {
        int s = (wv * 2 + j) * 64 + ln;
        int r = s >> 2;
        int q = (s & 3) ^ ((r >> 1) & 3);
        int m = m0 + r;
        int pm = ((m & 31) << 5) | (m >> 5);
        offA[j] = (size_t)pm * 512 + q * 8;
    }
#pragma unroll
    for (int j = 0; j < 4; ++j) {
        int s = (wv * 4 + j) * 64 + ln;
        int r = s >> 2;
        int q = (s & 3) ^ ((r >> 1) & 3);
        int m = n0 + r;
        int pm = ((m & 31) << 5) | (m >> 5);
        offB[j] = (size_t)pm * 512 + q * 8;
    }

    for (int kk = 0; kk < 512; kk += 32) {
        __syncthreads();
#pragma unroll
        for (int j = 0; j < 2; ++j)
            gl2lds16(Tb + offA[j] + kk, As + (size_t)(wv * 2 + j) * 512);
#pragma unroll
        for (int j = 0; j < 4; ++j)
            gl2lds16(Hb + offB[j] + kk, Bs + (size_t)(wv * 4 + j) * 512);
        __syncthreads();
        short8 af[4], bfr[8];
#pragma unroll
        for (int t = 0; t < 4; ++t) {
            int ra = wm + t * 16 + fr;
            af[t] = *(const short8*)(As + ra * 32 + ((fq ^ ((ra >> 1) & 3)) * 8));
        }
#pragma unroll
        for (int u = 0; u < 8; ++u) {
            int rb = wn + u * 16 + fr;
            bfr[u] = *(const short8*)(Bs + rb * 32 + ((fq ^ ((rb >> 1) & 3)) * 8));
        }
#pragma unroll
        for (int mt = 0; mt < 4; ++mt)
#pragma unroll
            for (int nt = 0; nt < 8; ++nt)
                acc[mt][nt] = MFMA16(af[mt], bfr[nt], acc[mt][nt]);
    }

    // ---- per-slice softmax-diagonal (2x4 = 8 slices per wave) ----
    const float scale = 0.04419417382415922f;  // 512^-0.5
    const float cst = cstp[0];
    const int wbase = (m0 + wm) >> 5;
    const int Wbase = (n0 + wn) >> 5;
#pragma unroll
    for (int si = 0; si < 2; ++si) {
#pragma unroll
        for (int sj = 0; sj < 4; ++sj) {
            int wg = wbase + si, Wg = Wbase + sj;
            float tv[16];
            float mx = -3.0e38f;
#pragma unroll
            for (int mi = 0; mi < 2; ++mi)
#pragma unroll
                for (int ni = 0; ni < 2; ++ni) {
                    float vc = v2p[b * 1024 + Wg * 32 + ni * 16 + fr];
#pragma unroll
                    for (int r = 0; r < 4; ++r) {
                        float uc = u1p[b * 1024 + wg * 32 + mi * 16 + fq * 4 + r];
                        float u = (acc[2 * si + mi][2 * sj + ni][r] + uc + vc + cst) * scale;
                        tv[(mi * 2 + ni) * 4 + r] = u;
                        mx = fmaxf(mx, u);
                    }
                }
#pragma unroll
            for (int off = 32; off > 0; off >>= 1) mx = fmaxf(mx, __shfl_xor(mx, off, 64));
            float se = 0.f;
#pragma unroll
            for (int i = 0; i < 16; ++i) se += __expf(tv[i] - mx);
#pragma unroll
            for (int off = 32; off > 0; off >>= 1) se += __shfl_xor(se, off, 64);
            if (fq == ((wg >> 2) & 3) && fr == (Wg & 15)) {
                int mi = wg >> 4, ni = Wg >> 4;
                float numer = tv[(mi * 2 + ni) * 4 + (wg & 3)];
                Dm[((size_t)b * 32 + wg) * 32 + Wg] = __expf(numer - mx) / se;
            }
        }
    }
}

// ---------------- fused out-GEMM: out[b][n][m] = x + D[b][m]*(V·Wn)[m][n] + bn[n] ----------------
__global__ __launch_bounds__(256) void out_gemm(const short* __restrict__ A,
                                                const short* __restrict__ Wt,
                                                const float* __restrict__ Dm,
                                                const float* __restrict__ bnb,
                                                const float* __restrict__ x,
                                                float* __restrict__ out) {
    const int tid = threadIdx.x;
    const int wv = tid >> 6, ln = tid & 63;
    int sid = blockIdx.x + 8 * (blockIdx.y + 4 * blockIdx.z);
    int xcd = sid & 7, chunk = sid >> 3;           // XCD batch-affinity swizzle
    int b = xcd * 2 + (chunk >> 5);
    int inner = chunk & 31;
    const int m0 = (inner & 7) * 128, n0 = (inner >> 3) * 128;
    const size_t BS = 1024 * 512;
    const short* Ab = A + (size_t)b * BS;

    __shared__ __attribute__((aligned(16))) short As[128 * 32];
    __shared__ __attribute__((aligned(16))) short Bs[128 * 32];

    floatx4 acc[4][4] = {};
    const int wm = (wv >> 1) * 64, wn = (wv & 1) * 64;
    const int fr = ln & 15, fq = ln >> 4;

    for (int kk = 0; kk < 512; kk += 32) {
        __syncthreads();
#pragma unroll
        for (int j = 0; j < 2; ++j) {
            int s = (wv * 2 + j) * 64 + ln;
            int r = s >> 2;
            int q = (s & 3) ^ ((r >> 1) & 3);
            gl2lds16(Ab + (size_t)(m0 + r) * 512 + kk + q * 8, As + (size_t)(wv * 2 + j) * 512);
            gl2lds16(Wt + (size_t)(n0 + r) * 512 + kk + q * 8, Bs + (size_t)(wv * 2 + j) * 512);
        }
        __syncthreads();
        short8 af[4], bfr[4];
#pragma unroll
        for (int t = 0; t < 4; ++t) {
            int ra = wm + t * 16 + fr;
            af[t]  = *(const short8*)(As + ra * 32 + ((fq ^ ((ra >> 1) & 3)) * 8));
            int rb = wn + t * 16 + fr;
            bfr[t] = *(const short8*)(Bs + rb * 32 + ((fq ^ ((rb >> 1) & 3)) * 8));
        }
#pragma unroll
        for (int mt = 0; mt < 4; ++mt)
#pragma unroll
            for (int nt = 0; nt < 4; ++nt)
                acc[mt][nt] = MFMA16(af[mt], bfr[nt], acc[mt][nt]);
    }
#pragma unroll
    for (int mt = 0; mt < 4; ++mt) {
        int mbase = m0 + wm + mt * 16 + fq * 4;
        float4 d4 = *(const float4*)(Dm + (size_t)b * 1024 + mbase);
#pragma unroll
        for (int nt = 0; nt < 4; ++nt) {
            int n = n0 + wn + nt * 16 + fr;
            float bvv = bnb[n];
            size_t base = ((size_t)b * 512 + n) * 1024 + mbase;
            float4 x4 = *(const float4*)(x + base);
            float4 o;
            o.x = x4.x + d4.x * acc[mt][nt][0] + bvv;
            o.y = x4.y + d4.y * acc[mt][nt][1] + bvv;
            o.z = x4.z + d4.z * acc[mt][nt][2] + bvv;
            o.w = x4.w + d4.w * acc[mt][nt][3] + bvv;
            *(float4*)(out + base) = o;
        }
    }
}

extern "C" void kernel_launch(void* const* d_in, const int* in_sizes, int n_in,
                              void* d_out, int out_size, void* d_ws, size_t ws_size,
                              hipStream_t stream) {
    const float* x  = (const float*)d_in[0];
    const float* Wq = (const float*)d_in[1];
    const float* bq = (const float*)d_in[2];
    const float* Wk = (const float*)d_in[3];
    const float* bk = (const float*)d_in[4];
    const float* Wv = (const float*)d_in[5];
    const float* bv = (const float*)d_in[6];
    const float* Wn = (const float*)d_in[7];
    const float* bn = (const float*)d_in[8];
    float* out = (float*)d_out;
    char* ws = (char*)d_ws;

    const size_t WSZ = (size_t)512 * 512 * 2;        // bf16 512x512
    const size_t TSZ = (size_t)16 * 1024 * 512 * 2;  // bf16 activation tensor
    short* Wtv  = (short*)(ws);                      // [1024][512]: G rows 0-511, Wv_t rows 512-1023
    short* Wn_t = (short*)(ws + 2 * WSZ);
    float* wu   = (float*)(ws + 3 * WSZ);            // 512
    float* wv2  = wu + 512;                          // 512
    float* cstp = wv2 + 512;                         // 16 (pad)
    float* u1p  = cstp + 16;                         // 16384
    float* v2p  = u1p + 16384;                       // 16384
    char* base = ws + 3 * WSZ + 139264;              // small region padded to 136 KB
    short* hnt = (short*)(base);
    short* T   = (short*)(base + TSZ);
    short* Vb  = (short*)(base + 2 * TSZ);
    float* Dm  = (float*)(base + 3 * TSZ);           // 64 KB
    // wqb/wkb alias the head of T (dead before tv_gemm writes T; g_gemm finishes first)
    short* wqb = T;
    short* wkb = T + 512 * 512;

    prep_w<<<dim3(16, 16, 5), dim3(32, 8), 0, stream>>>(
        Wq, Wk, Wv, Wn, bq, bk, wqb, wkb, Wtv, Wn_t, wu, wv2, cstp);
    g_gemm<<<dim3(4, 4, 1), 256, 0, stream>>>(wkb, wqb, Wtv);
    groupnorm_k<<<512, 256, 0, stream>>>(x, hnt);
    uv_gemv<<<4096, 256, 0, stream>>>(hnt, wu, wv2, u1p, v2p);
    tv_gemm<<<dim3(8, 8, 16), 256, 0, stream>>>(hnt, Wtv, bv, T, Vb);
    attn_sm<<<dim3(8, 4, 16), 256, 0, stream>>>(T, hnt, u1p, v2p, cstp, Dm);
    out_gemm<<<dim3(8, 4, 16), 256, 0, stream>>>(Vb, Wn_t, Dm, bn, x, out);
}

// Round 7
// 217.767 us; speedup vs baseline: 1.1226x; 1.0080x over previous
//
#include <hip/hip_runtime.h>
#include <hip/hip_bf16.h>

typedef __attribute__((ext_vector_type(8))) short short8;
typedef __attribute__((ext_vector_type(4))) float floatx4;

#define MFMA16(a, b, c) __builtin_amdgcn_mfma_f32_16x16x32_bf16((a), (b), (c), 0, 0, 0)

__device__ __forceinline__ short f2bf(float f) {
    union { float f; unsigned u; } x; x.f = f;
    unsigned r = (x.u + 0x7fffu + ((x.u >> 16) & 1u)) >> 16;
    return (short)r;
}
__device__ __forceinline__ float bf2f(short s) {
    union { float f; unsigned u; } x; x.u = ((unsigned)(unsigned short)s) << 16;
    return x.f;
}

// async global->LDS, 16B per lane; LDS dest is wave-uniform base + lane*16
__device__ __forceinline__ void gl2lds16(const short* g, short* l) {
    void* gv = const_cast<short*>(g);
    __builtin_amdgcn_global_load_lds((__attribute__((address_space(1))) void*)gv,
                                     (__attribute__((address_space(3))) void*)l,
                                     16, 0, 0);
}

// ================= K1: groupnorm ∪ weight-prep ∪ bias-dots (all independent) =================
// blocks [0,512): groupnorm x->hnt ; [512,1536): weight copies/transposes ; [1536,1552): dots
__global__ __launch_bounds__(256) void fused_prep(const float* __restrict__ x,
                                                  const float* __restrict__ Wq,
                                                  const float* __restrict__ Wk,
                                                  const float* __restrict__ Wv,
                                                  const float* __restrict__ Wn,
                                                  const float* __restrict__ bq,
                                                  const float* __restrict__ bk,
                                                  short* __restrict__ hnt,
                                                  short* __restrict__ wqb,
                                                  short* __restrict__ wkb,
                                                  short* __restrict__ Wtv,
                                                  short* __restrict__ Wn_t,
                                                  float* __restrict__ wu,
                                                  float* __restrict__ wv2,
                                                  float* __restrict__ cstp) {
    __shared__ __attribute__((aligned(16))) short tile[16 * 1026];
    __shared__ float red[8];
    __shared__ float t[32][33];
    __shared__ float cred[4];
    const int bid = blockIdx.x, tid = threadIdx.x;

    if (bid < 512) {
        // ---- groupnorm (R2-proven) ----
        int b = bid >> 5, g = bid & 31;
        const float* xg = x + ((size_t)b * 512 + g * 16) * 1024;
        const float4* xg4 = (const float4*)xg;
        float s = 0.f, ss = 0.f;
        for (int i = tid; i < 4096; i += 256) {
            float4 v = xg4[i];
            s  += v.x + v.y + v.z + v.w;
            ss += v.x * v.x + v.y * v.y + v.z * v.z + v.w * v.w;
        }
#pragma unroll
        for (int off = 32; off > 0; off >>= 1) {
            s  += __shfl_down(s,  off, 64);
            ss += __shfl_down(ss, off, 64);
        }
        int w = tid >> 6;
        if ((tid & 63) == 0) { red[w] = s; red[4 + w] = ss; }
        __syncthreads();
        float S  = red[0] + red[1] + red[2] + red[3];
        float SS = red[4] + red[5] + red[6] + red[7];
        float mean = S * (1.f / 16384.f);
        float var  = SS * (1.f / 16384.f) - mean * mean;
        float rstd = rsqrtf(var + 1e-5f);
        for (int i = tid; i < 4096; i += 256) {
            float4 v = xg4[i];
            int c = i >> 8, p = (i & 255) * 4;
            short* tp = tile + c * 1026 + p;
            tp[0] = f2bf((v.x - mean) * rstd);
            tp[1] = f2bf((v.y - mean) * rstd);
            tp[2] = f2bf((v.z - mean) * rstd);
            tp[3] = f2bf((v.w - mean) * rstd);
        }
        __syncthreads();
        for (int i = tid; i < 2048; i += 256) {
            int p = i >> 1, half = i & 1;
            short8 v;
#pragma unroll
            for (int j = 0; j < 8; ++j) v[j] = tile[(half * 8 + j) * 1026 + p];
            *(short8*)(hnt + ((size_t)b * 1024 + p) * 512 + g * 16 + half * 8) = v;
        }
    } else if (bid < 1536) {
        // ---- weight copies / transposes ----
        int tz = bid - 512;
        int z = tz >> 8, inner = tz & 255;
        int o0 = (inner & 15) * 32, c0 = (inner >> 4) * 32;
        int lx = tid & 31, ly = tid >> 5;   // (32,8)
        if (z < 2) {
            const float* src = z ? Wk : Wq;
            short* dst = z ? wkb : wqb;
            for (int i = ly; i < 32; i += 8)
                dst[(size_t)(c0 + i) * 512 + o0 + lx] = f2bf(src[(size_t)(c0 + i) * 512 + o0 + lx]);
        } else {
            const float* src = (z == 2) ? Wv : Wn;
            short* dst = (z == 2) ? (Wtv + (size_t)512 * 512) : Wn_t;
            for (int i = ly; i < 32; i += 8) t[i][lx] = src[(size_t)(c0 + i) * 512 + o0 + lx];
            __syncthreads();
            for (int i = ly; i < 32; i += 8) dst[(size_t)(o0 + i) * 512 + c0 + lx] = f2bf(t[lx][i]);
        }
    } else {
        // ---- bias-fold dots: wu = Wq·bk, wv2 = Wk·bq, cst = bq·bk ----
        int bid3 = bid - 1536;
        int cb = bid3 * 32;
        int cl = tid >> 3, part = tid & 7;    // 8 partial sums per channel
        float su = 0.f, sv = 0.f;
        const float* wqr = Wq + (size_t)(cb + cl) * 512;
        const float* wkr = Wk + (size_t)(cb + cl) * 512;
        for (int o = part * 64; o < part * 64 + 64; ++o) {
            su += wqr[o] * bk[o];
            sv += wkr[o] * bq[o];
        }
        t[cl][part] = su;
        t[cl][part + 8] = sv;
        float sc = 0.f;
        if (bid3 == 0) sc = bq[tid] * bk[tid] + bq[tid + 256] * bk[tid + 256];
#pragma unroll
        for (int off = 32; off > 0; off >>= 1) sc += __shfl_down(sc, off, 64);
        if ((tid & 63) == 0) cred[tid >> 6] = sc;
        __syncthreads();
        if (part == 0) {
            float a = 0.f, b2 = 0.f;
#pragma unroll
            for (int j = 0; j < 8; ++j) { a += t[cl][j]; b2 += t[cl][j + 8]; }
            wu[cb + cl] = a;
            wv2[cb + cl] = b2;
        }
        if (bid3 == 0 && tid == 0) cstp[0] = cred[0] + cred[1] + cred[2] + cred[3];
    }
}

// ================= K2: g_gemm ∪ uv_gemv (independent given K1) =================
// blocks [0,16): G = Wk·Wq^T into Wtv rows [0,512). blocks [16,528): u1p/v2p row dots.
__global__ __launch_bounds__(256) void fused_gu(const short* __restrict__ wkb,
                                                const short* __restrict__ wqb,
                                                short* __restrict__ Wtv,
                                                const short* __restrict__ hnt,
                                                const float* __restrict__ wu,
                                                const float* __restrict__ wv2,
                                                float* __restrict__ u1p,
                                                float* __restrict__ v2p) {
    __shared__ __attribute__((aligned(16))) short As[128 * 32];
    __shared__ __attribute__((aligned(16))) short Bs[128 * 32];
    const int tid = threadIdx.x;
    const int wv = tid >> 6, ln = tid & 63;

    if (blockIdx.x < 16) {
        const int m0 = (blockIdx.x & 3) * 128, n0 = (blockIdx.x >> 2) * 128;
        floatx4 acc[4][4] = {};
        const int wm = (wv >> 1) * 64, wn = (wv & 1) * 64;
        const int fr = ln & 15, fq = ln >> 4;
        for (int kk = 0; kk < 512; kk += 32) {
            __syncthreads();
#pragma unroll
            for (int j = 0; j < 2; ++j) {
                int s = (wv * 2 + j) * 64 + ln;
                int r = s >> 2;
                int q = (s & 3) ^ ((r >> 1) & 3);
                gl2lds16(wkb + (size_t)(m0 + r) * 512 + kk + q * 8, As + (size_t)(wv * 2 + j) * 512);
                gl2lds16(wqb + (size_t)(n0 + r) * 512 + kk + q * 8, Bs + (size_t)(wv * 2 + j) * 512);
            }
            __syncthreads();
            short8 af[4], bfr[4];
#pragma unroll
            for (int t = 0; t < 4; ++t) {
                int ra = wm + t * 16 + fr;
                af[t]  = *(const short8*)(As + ra * 32 + ((fq ^ ((ra >> 1) & 3)) * 8));
                int rb = wn + t * 16 + fr;
                bfr[t] = *(const short8*)(Bs + rb * 32 + ((fq ^ ((rb >> 1) & 3)) * 8));
            }
#pragma unroll
            for (int mt = 0; mt < 4; ++mt)
#pragma unroll
                for (int nt = 0; nt < 4; ++nt)
                    acc[mt][nt] = MFMA16(af[mt], bfr[nt], acc[mt][nt]);
        }
#pragma unroll
        for (int mt = 0; mt < 4; ++mt)
#pragma unroll
            for (int nt = 0; nt < 4; ++nt) {
                int n = n0 + wn + nt * 16 + fr;
                const int fq2 = ln >> 4;
#pragma unroll
                for (int r = 0; r < 4; ++r) {
                    int m = m0 + wm + mt * 16 + fq2 * 4 + r;
                    Wtv[(size_t)m * 512 + n] = f2bf(acc[mt][nt][r]);
                }
            }
    } else {
        // uv_gemv: wu/wv2 in registers, 8 rows per wave
        const float4* wu4 = (const float4*)wu;
        const float4* wv4 = (const float4*)wv2;
        float4 u0 = wu4[ln * 2], u1 = wu4[ln * 2 + 1];
        float4 v0 = wv4[ln * 2], v1 = wv4[ln * 2 + 1];
        int base_row = (blockIdx.x - 16) * 32 + wv * 8;
#pragma unroll
        for (int rr = 0; rr < 8; ++rr) {
            int row = base_row + rr;
            int b = row >> 10, p = row & 1023;
            short8 h = *(const short8*)(hnt + (size_t)row * 512 + ln * 8);
            float su = bf2f(h[0]) * u0.x + bf2f(h[1]) * u0.y + bf2f(h[2]) * u0.z + bf2f(h[3]) * u0.w
                     + bf2f(h[4]) * u1.x + bf2f(h[5]) * u1.y + bf2f(h[6]) * u1.z + bf2f(h[7]) * u1.w;
            float sv = bf2f(h[0]) * v0.x + bf2f(h[1]) * v0.y + bf2f(h[2]) * v0.z + bf2f(h[3]) * v0.w
                     + bf2f(h[4]) * v1.x + bf2f(h[5]) * v1.y + bf2f(h[6]) * v1.z + bf2f(h[7]) * v1.w;
#pragma unroll
            for (int off = 32; off > 0; off >>= 1) {
                su += __shfl_down(su, off, 64);
                sv += __shfl_down(sv, off, 64);
            }
            if (ln == 0) {
                int pp = ((p & 31) << 5) | (p >> 5);
                u1p[b * 1024 + pp] = su;
                v2p[b * 1024 + pp] = sv;
            }
        }
    }
}

// ------------- fused T/V GEMM: 128x128, N=1024 over [G ; Wv_t], natural writes -------------
__global__ __launch_bounds__(256) void tv_gemm(const short* __restrict__ A,
                                               const short* __restrict__ Wt,
                                               const float* __restrict__ bv,
                                               short* __restrict__ T,
                                               short* __restrict__ Vb) {
    const int tid = threadIdx.x;
    const int wv = tid >> 6, ln = tid & 63;
    int sid = blockIdx.x + 8 * (blockIdx.y + 8 * blockIdx.z);
    int xcd = sid & 7, chunk = sid >> 3;           // XCD batch-affinity swizzle
    int bz = xcd * 2 + (chunk >> 6);
    int inner = chunk & 63;
    const int m0 = (inner & 7) * 128, n0 = (inner >> 3) * 128;
    const size_t BS = 1024 * 512;
    const short* Ab = A + (size_t)bz * BS;
    const int tsel = n0 >> 9;
    short* Ob = (tsel ? Vb : T) + (size_t)bz * BS;

    __shared__ __attribute__((aligned(16))) short As[128 * 32];
    __shared__ __attribute__((aligned(16))) short Bs[128 * 32];

    floatx4 acc[4][4] = {};
    const int wm = (wv >> 1) * 64, wn = (wv & 1) * 64;
    const int fr = ln & 15, fq = ln >> 4;

    for (int kk = 0; kk < 512; kk += 32) {
        __syncthreads();
#pragma unroll
        for (int j = 0; j < 2; ++j) {
            int s = (wv * 2 + j) * 64 + ln;
            int r = s >> 2;
            int q = (s & 3) ^ ((r >> 1) & 3);
            gl2lds16(Ab + (size_t)(m0 + r) * 512 + kk + q * 8, As + (size_t)(wv * 2 + j) * 512);
            gl2lds16(Wt + (size_t)(n0 + r) * 512 + kk + q * 8, Bs + (size_t)(wv * 2 + j) * 512);
        }
        __syncthreads();
        short8 af[4], bfr[4];
#pragma unroll
        for (int t = 0; t < 4; ++t) {
            int ra = wm + t * 16 + fr;
            af[t]  = *(const short8*)(As + ra * 32 + ((fq ^ ((ra >> 1) & 3)) * 8));
            int rb = wn + t * 16 + fr;
            bfr[t] = *(const short8*)(Bs + rb * 32 + ((fq ^ ((rb >> 1) & 3)) * 8));
        }
#pragma unroll
        for (int mt = 0; mt < 4; ++mt)
#pragma unroll
            for (int nt = 0; nt < 4; ++nt)
                acc[mt][nt] = MFMA16(af[mt], bfr[nt], acc[mt][nt]);
    }
#pragma unroll
    for (int mt = 0; mt < 4; ++mt)
#pragma unroll
        for (int nt = 0; nt < 4; ++nt) {
            int n = n0 + wn + nt * 16 + fr;
            float bvv = tsel ? bv[n - 512] : 0.0f;
            int nn = n & 511;
#pragma unroll
            for (int r = 0; r < 4; ++r) {
                int m = m0 + wm + mt * 16 + fq * 4 + r;
                Ob[(size_t)m * 512 + nn] = f2bf(acc[mt][nt][r] + bvv);
            }
        }
}

// ------- fused S-GEMM + softmax diagonal; no max-subtraction (scores bounded ~|2|) -------
__global__ __launch_bounds__(256, 2) void attn_sm(const short* __restrict__ Tt,
                                                  const short* __restrict__ Hn,
                                                  const float* __restrict__ u1p,
                                                  const float* __restrict__ v2p,
                                                  const float* __restrict__ cstp,
                                                  float* __restrict__ Dm) {
    const int tid = threadIdx.x;
    const int wv = tid >> 6, ln = tid & 63;
    int sid = blockIdx.x + 8 * (blockIdx.y + 4 * blockIdx.z);
    int xcd = sid & 7, chunk = sid >> 3;           // XCD batch-affinity swizzle
    int b = xcd * 2 + (chunk >> 5);
    int inner = chunk & 31;
    const int m0 = (inner & 7) * 128, n0 = (inner >> 3) * 256;
    const short* Tb = Tt + (size_t)b * (1024 * 512);
    const short* Hb = Hn + (size_t)b * (1024 * 512);

    __shared__ __attribute__((aligned(16))) short As[128 * 32];
    __shared__ __attribute__((aligned(16))) short Bs[256 * 32];

    floatx4 acc[4][8] = {};
    const int wm = (wv >> 1) * 64, wn = (wv & 1) * 128;
    const int fr = ln & 15, fq = ln >> 4;

    // loop-invariant staging offsets (permuted source rows)
    size_t offA[2], offB[4];
#pragma unroll
    for (int j = 0; j < 2; ++j) {
        int s = (wv * 2 + j) * 64 + ln;
        int r = s >> 2;
        int q = (s & 3) ^ ((r >> 1) & 3);
        int m = m0 + r;
        int pm = ((m & 31) << 5) | (m >> 5);
        offA[j] = (size_t)pm * 512 + q * 8;
    }
#pragma unroll
    for (int j = 0; j < 4; ++j) {
        int s = (wv * 4 + j) * 64 + ln;
        int r = s >> 2;
        int q = (s & 3) ^ ((r >> 1) & 3);
        int m = n0 + r;
        int pm = ((m & 31) << 5) | (m >> 5);
        offB[j] = (size_t)pm * 512 + q * 8;
    }

    for (int kk = 0; kk < 512; kk += 32) {
        __syncthreads();
#pragma unroll
        for (int j = 0; j < 2; ++j)
            gl2lds16(Tb + offA[j] + kk, As + (size_t)(wv * 2 + j) * 512);
#pragma unroll
        for (int j = 0; j < 4; ++j)
            gl2lds16(Hb + offB[j] + kk, Bs + (size_t)(wv * 4 + j) * 512);
        __syncthreads();
        short8 af[4], bfr[8];
#pragma unroll
        for (int t = 0; t < 4; ++t) {
            int ra = wm + t * 16 + fr;
            af[t] = *(const short8*)(As + ra * 32 + ((fq ^ ((ra >> 1) & 3)) * 8));
        }
#pragma unroll
        for (int u = 0; u < 8; ++u) {
            int rb = wn + u * 16 + fr;
            bfr[u] = *(const short8*)(Bs + rb * 32 + ((fq ^ ((rb >> 1) & 3)) * 8));
        }
#pragma unroll
        for (int mt = 0; mt < 4; ++mt)
#pragma unroll
            for (int nt = 0; nt < 8; ++nt)
                acc[mt][nt] = MFMA16(af[mt], bfr[nt], acc[mt][nt]);
    }

    // ---- per-slice softmax-diagonal, no max-shift (2x4 = 8 slices per wave) ----
    const float scale = 0.04419417382415922f;  // 512^-0.5
    const float cst = cstp[0];
    const int wbase = (m0 + wm) >> 5;
    const int Wbase = (n0 + wn) >> 5;
#pragma unroll
    for (int si = 0; si < 2; ++si) {
#pragma unroll
        for (int sj = 0; sj < 4; ++sj) {
            int wg = wbase + si, Wg = Wbase + sj;
            float ex[16];
            float se = 0.f;
#pragma unroll
            for (int mi = 0; mi < 2; ++mi)
#pragma unroll
                for (int ni = 0; ni < 2; ++ni) {
                    float vc = v2p[b * 1024 + Wg * 32 + ni * 16 + fr];
#pragma unroll
                    for (int r = 0; r < 4; ++r) {
                        float uc = u1p[b * 1024 + wg * 32 + mi * 16 + fq * 4 + r];
                        float e = __expf((acc[2 * si + mi][2 * sj + ni][r] + uc + vc + cst) * scale);
                        ex[(mi * 2 + ni) * 4 + r] = e;
                        se += e;
                    }
                }
#pragma unroll
            for (int off = 32; off > 0; off >>= 1) se += __shfl_xor(se, off, 64);
            if (fq == ((wg >> 2) & 3) && fr == (Wg & 15)) {
                int mi = wg >> 4, ni = Wg >> 4;
                Dm[((size_t)b * 32 + wg) * 32 + Wg] = ex[(mi * 2 + ni) * 4 + (wg & 3)] / se;
            }
        }
    }
}

// ---------------- fused out-GEMM: out[b][n][m] = x + D[b][m]*(V·Wn)[m][n] + bn[n] ----------------
__global__ __launch_bounds__(256) void out_gemm(const short* __restrict__ A,
                                                const short* __restrict__ Wt,
                                                const float* __restrict__ Dm,
                                                const float* __restrict__ bnb,
                                                const float* __restrict__ x,
                                                float* __restrict__ out) {
    const int tid = threadIdx.x;
    const int wv = tid >> 6, ln = tid & 63;
    int sid = blockIdx.x + 8 * (blockIdx.y + 4 * blockIdx.z);
    int xcd = sid & 7, chunk = sid >> 3;           // XCD batch-affinity swizzle
    int b = xcd * 2 + (chunk >> 5);
    int inner = chunk & 31;
    const int m0 = (inner & 7) * 128, n0 = (inner >> 3) * 128;
    const size_t BS = 1024 * 512;
    const short* Ab = A + (size_t)b * BS;

    __shared__ __attribute__((aligned(16))) short As[128 * 32];
    __shared__ __attribute__((aligned(16))) short Bs[128 * 32];

    floatx4 acc[4][4] = {};
    const int wm = (wv >> 1) * 64, wn = (wv & 1) * 64;
    const int fr = ln & 15, fq = ln >> 4;

    for (int kk = 0; kk < 512; kk += 32) {
        __syncthreads();
#pragma unroll
        for (int j = 0; j < 2; ++j) {
            int s = (wv * 2 + j) * 64 + ln;
            int r = s >> 2;
            int q = (s & 3) ^ ((r >> 1) & 3);
            gl2lds16(Ab + (size_t)(m0 + r) * 512 + kk + q * 8, As + (size_t)(wv * 2 + j) * 512);
            gl2lds16(Wt + (size_t)(n0 + r) * 512 + kk + q * 8, Bs + (size_t)(wv * 2 + j) * 512);
        }
        __syncthreads();
        short8 af[4], bfr[4];
#pragma unroll
        for (int t = 0; t < 4; ++t) {
            int ra = wm + t * 16 + fr;
            af[t]  = *(const short8*)(As + ra * 32 + ((fq ^ ((ra >> 1) & 3)) * 8));
            int rb = wn + t * 16 + fr;
            bfr[t] = *(const short8*)(Bs + rb * 32 + ((fq ^ ((rb >> 1) & 3)) * 8));
        }
#pragma unroll
        for (int mt = 0; mt < 4; ++mt)
#pragma unroll
            for (int nt = 0; nt < 4; ++nt)
                acc[mt][nt] = MFMA16(af[mt], bfr[nt], acc[mt][nt]);
    }
#pragma unroll
    for (int mt = 0; mt < 4; ++mt) {
        int mbase = m0 + wm + mt * 16 + fq * 4;
        float4 d4 = *(const float4*)(Dm + (size_t)b * 1024 + mbase);
#pragma unroll
        for (int nt = 0; nt < 4; ++nt) {
            int n = n0 + wn + nt * 16 + fr;
            float bvv = bnb[n];
            size_t base = ((size_t)b * 512 + n) * 1024 + mbase;
            float4 x4 = *(const float4*)(x + base);
            float4 o;
            o.x = x4.x + d4.x * acc[mt][nt][0] + bvv;
            o.y = x4.y + d4.y * acc[mt][nt][1] + bvv;
            o.z = x4.z + d4.z * acc[mt][nt][2] + bvv;
            o.w = x4.w + d4.w * acc[mt][nt][3] + bvv;
            *(float4*)(out + base) = o;
        }
    }
}

extern "C" void kernel_launch(void* const* d_in, const int* in_sizes, int n_in,
                              void* d_out, int out_size, void* d_ws, size_t ws_size,
                              hipStream_t stream) {
    const float* x  = (const float*)d_in[0];
    const float* Wq = (const float*)d_in[1];
    const float* bq = (const float*)d_in[2];
    const float* Wk = (const float*)d_in[3];
    const float* bk = (const float*)d_in[4];
    const float* Wv = (const float*)d_in[5];
    const float* bv = (const float*)d_in[6];
    const float* Wn = (const float*)d_in[7];
    const float* bn = (const float*)d_in[8];
    float* out = (float*)d_out;
    char* ws = (char*)d_ws;

    const size_t WSZ = (size_t)512 * 512 * 2;        // bf16 512x512
    const size_t TSZ = (size_t)16 * 1024 * 512 * 2;  // bf16 activation tensor
    short* Wtv  = (short*)(ws);                      // [1024][512]: G rows 0-511, Wv_t rows 512-1023
    short* Wn_t = (short*)(ws + 2 * WSZ);
    float* wu   = (float*)(ws + 3 * WSZ);            // 512
    float* wv2  = wu + 512;                          // 512
    float* cstp = wv2 + 512;                         // 16 (pad)
    float* u1p  = cstp + 16;                         // 16384
    float* v2p  = u1p + 16384;                       // 16384
    char* base = ws + 3 * WSZ + 139264;              // small region padded to 136 KB
    short* hnt = (short*)(base);
    short* T   = (short*)(base + TSZ);
    short* Vb  = (short*)(base + 2 * TSZ);
    float* Dm  = (float*)(base + 3 * TSZ);           // 64 KB
    // wqb/wkb alias the head of T (dead before tv_gemm writes T; fused_gu finishes first)
    short* wqb = T;
    short* wkb = T + 512 * 512;

    fused_prep<<<1552, 256, 0, stream>>>(x, Wq, Wk, Wv, Wn, bq, bk,
                                         hnt, wqb, wkb, Wtv, Wn_t, wu, wv2, cstp);
    fused_gu<<<528, 256, 0, stream>>>(wkb, wqb, Wtv, hnt, wu, wv2, u1p, v2p);
    tv_gemm<<<dim3(8, 8, 16), 256, 0, stream>>>(hnt, Wtv, bv, T, Vb);
    attn_sm<<<dim3(8, 4, 16), 256, 0, stream>>>(T, hnt, u1p, v2p, cstp, Dm);
    out_gemm<<<dim3(8, 4, 16), 256, 0, stream>>>(Vb, Wn_t, Dm, bn, x, out);
}